// Round 4
// baseline (14110.420 us; speedup 1.0000x reference)
//
#include <hip/hip_runtime.h>

// OR_LSTM: 2-layer LSTM autoregressive rollout, wavefront-pipelined.
// B=32, T=128, D=16, H=256, WS=8, OUT=8. 120 windows over 127 iterations;
// at iter g, slots 0..7 (windows g-7..g) each advance one step.
// Round 4: latency-war edition.
//  - bulk GEMMs (ctrl + h0prev + h1prev parts) hoisted BEFORE the out-column
//    wait; only the rank-8 feedback injection + h0'-dependent GEMM are on the
//    serial chain.
//  - pair-scope (32 wg) leader-tree barriers: per-wg arrival lines, leader
//    polls with 31 lanes, replicated release lines (1 poller/line).
//  - head computed by pair leader alone after bar2 (no psum/PCNT atomics);
//    RDY replicated to 256 lines (1 poller/line).

#define NWG 256
#define TPB 512

// ---- control region (u32 indices, zeroed by hipMemsetAsync) ----
#define ARR_U(p, w)   (((p) * 32 + (w)) * 16)            // arrival lines
#define RELB_U(p, w)  (4096 + ((p) * 32 + (w)) * 16)     // release lines
#define RDY_U(w)      (8192 + (w) * 16)                  // 256 ready lines
#define CTRL_BYTES    49152

// ---- float indices ----
#define H0A_F   16384
#define H0B_F   (H0A_F + 65536)
#define C0_F    (H0B_F + 65536)
#define H1A_F   (C0_F + 65536)
#define H1B_F   (H1A_F + 65536)
#define C1_F    (H1B_F + 65536)
// packed weights: PW[uc][kb4][c][kk] (uc stride 16384 floats)
#define PWHH0_F (C1_F + 65536)
#define PWIH1_F (PWHH0_F + 262144)
#define PWHH1_F (PWIH1_F + 262144)
#define PWIH0_F (PWHH1_F + 262144)   // [uc][k][c], k<16 (uc stride 1024)
// total ~4.63 MiB

__device__ __forceinline__ float sigf(float x) { return 1.0f / (1.0f + __expf(-x)); }
__device__ __forceinline__ float tanhfast(float x) {
  float e = __expf(2.0f * x);
  return 1.0f - 2.0f / (e + 1.0f);
}
__device__ __forceinline__ unsigned rload(const unsigned* p) {
  return __hip_atomic_load(p, __ATOMIC_RELAXED, __HIP_MEMORY_SCOPE_AGENT);
}
__device__ __forceinline__ void rstore(unsigned* p, unsigned v) {
  __hip_atomic_store(p, v, __ATOMIC_RELAXED, __HIP_MEMORY_SCOPE_AGENT);
}

// Pair-scope (32 wg) leader-tree barrier. Entry __syncthreads drains vmcnt
// for every wave (stores L2-visible) before arrival is posted.
__device__ __forceinline__ void pairbar(unsigned* ctrl, int pair, int widx,
                                        unsigned seq) {
  __syncthreads();
  const int tid = threadIdx.x;
  if (widx == 0) {
    if (tid >= 1 && tid < 32) {
      const unsigned* a = &ctrl[ARR_U(pair, tid)];
      while (rload(a) < seq) __builtin_amdgcn_s_sleep(1);
    }
    __syncthreads();
    if (tid >= 1 && tid < 32) rstore(&ctrl[RELB_U(pair, tid)], seq);
    if (tid == 0) __threadfence();
    __syncthreads();
  } else {
    if (tid == 0) {
      rstore(&ctrl[ARR_U(pair, widx)], seq);
      while (rload(&ctrl[RELB_U(pair, widx)]) < seq)
        __builtin_amdgcn_s_sleep(1);
      __threadfence();
    }
    __syncthreads();
  }
}

// Pack weights: PW[uc][kb4][c][kk] = W[j(c,uc)][kb4*4+kk].
__global__ __launch_bounds__(256) void lstm_prep(
    const float* __restrict__ Wih0, const float* __restrict__ Whh0,
    const float* __restrict__ Wih1, const float* __restrict__ Whh1,
    float* __restrict__ wsf) {
  const int i = blockIdx.x * 256 + threadIdx.x;
  if (i < 262144) {
    const int uc  = i >> 14;
    const int kb4 = (i >> 8) & 63;
    const int c   = (i >> 2) & 63;
    const int kk  = i & 3;
    const int k   = kb4 * 4 + kk;
    const int j   = (c >> 4) * 256 + uc * 16 + (c & 15);
    wsf[PWHH0_F + i] = Whh0[j * 256 + k];
    wsf[PWIH1_F + i] = Wih1[j * 256 + k];
    wsf[PWHH1_F + i] = Whh1[j * 256 + k];
    if (k < 16) wsf[PWIH0_F + uc * 1024 + k * 64 + c] = Wih0[j * 16 + k];
  }
}

__global__ __launch_bounds__(TPB, 2) void lstm_main(
    const float* __restrict__ traj,
    const float* __restrict__ bih0, const float* __restrict__ bhh0,
    const float* __restrict__ bih1, const float* __restrict__ bhh1,
    const float* __restrict__ Wlin, const float* __restrict__ blin,
    float* __restrict__ out, float* __restrict__ wsf) {
  // big: staging (h0prev|h1prev or h0') then partial planes. 38.6 KB total.
  __shared__ float big[8192];
  __shared__ float sh_x[256];
  __shared__ float sh_g[1024];
  __shared__ float sh_o[128];

  const int tid = threadIdx.x;
  const int wg  = blockIdx.x;
  const int rt  = wg >> 4;          // row tile (16 rows), 0..15
  const int uc  = wg & 15;          // unit chunk (16 hidden units)
  const int pair    = rt >> 1;      // pipeline slot 0..7
  const int widx    = (rt & 1) * 16 + uc;   // 0..31 within pair
  const int rowBase = rt << 4;

  const int ks = tid >> 6;          // K-split 0..7 (wave id)
  const int c  = tid & 63;          // packed col 0..63

  unsigned* ctrl = (unsigned*)wsf;

  const float4* PW_hh0 = (const float4*)(wsf + PWHH0_F + uc * 16384);
  const float4* PW_ih1 = (const float4*)(wsf + PWIH1_F + uc * 16384);
  const float4* PW_hh1 = (const float4*)(wsf + PWHH1_F + uc * 16384);
  const float*  PW_ih0 = wsf + PWIH0_F + uc * 1024;

  unsigned seq = 0;
  float acc1[16], acc2[16];

  for (int g = 0; g < 127; ++g) {
    const int s = (g - pair) & 7;
    const int t = g - s;
    const bool valid = (t >= 0) && (t <= 119);
    const bool fresh = (s == 0) || (!valid);
    const int p = g & 1;

    // ============ PREWORK (off the out-column chain) ============
    if (tid < 256) {  // stage x: ctrl part only (fb dims injected later)
      const int r = tid >> 4, d = tid & 15;
      const int b = (rowBase + r) & 31;
      float xv = 0.0f;
      if (valid) {
        if (t <= 7 && s < 8 - t) {
          xv = traj[b * 2048 + (t + s) * 16 + d];   // raw window (g<8 only)
        } else if (d < 8) {
          const int ti = (t <= 7) ? (2 * t + s - 1) : (t + s);
          xv = traj[b * 2048 + ti * 16 + d];
        }
      }
      sh_x[tid] = xv;
    }
    {  // stage h0prev -> big[0:4096], h1prev -> big[4096:8192]
      const float* h0r = wsf + (p ? H0B_F : H0A_F) + rowBase * 256;
      const float* h1r = wsf + (p ? H1B_F : H1A_F) + rowBase * 256;
      float4* B4 = (float4*)big;
#pragma unroll
      for (int i = 0; i < 2; ++i) {
        const int idx = tid + i * 512;
        float4 v0 = make_float4(0.f, 0.f, 0.f, 0.f);
        float4 v1 = v0;
        if (!fresh) {
          v0 = ((const float4*)h0r)[idx];
          v1 = ((const float4*)h1r)[idx];
        }
        B4[idx] = v0;
        B4[1024 + idx] = v1;
      }
    }
    __syncthreads();

#pragma unroll
    for (int r = 0; r < 16; ++r) { acc1[r] = 0.f; acc2[r] = 0.f; }
    {  // bulk A: Wih0·x_ctrl (K=16; fb dims are zero)
#pragma unroll
      for (int kk = 0; kk < 2; ++kk) {
        const int k = ks * 2 + kk;
        const float w = PW_ih0[k * 64 + c];
#pragma unroll
        for (int r = 0; r < 16; ++r)
          acc1[r] = fmaf(sh_x[r * 16 + k], w, acc1[r]);
      }
    }
    {  // bulk A: Whh0·h0prev  +  bulk B: Whh1·h1prev (both K=256)
      const float4* A4 = (const float4*)big;
      const float4* B4 = A4 + 1024;
#pragma unroll
      for (int kc = 0; kc < 8; ++kc) {
        const int kb4 = ks * 8 + kc;
        const float4 wa = PW_hh0[kb4 * 64 + c];
        const float4 wb = PW_hh1[kb4 * 64 + c];
#pragma unroll
        for (int r = 0; r < 16; ++r) {
          const float4 a4 = A4[r * 64 + kb4];
          const float4 b4 = B4[r * 64 + kb4];
          acc1[r] = fmaf(a4.x, wa.x, acc1[r]);
          acc1[r] = fmaf(a4.y, wa.y, acc1[r]);
          acc1[r] = fmaf(a4.z, wa.z, acc1[r]);
          acc1[r] = fmaf(a4.w, wa.w, acc1[r]);
          acc2[r] = fmaf(b4.x, wb.x, acc2[r]);
          acc2[r] = fmaf(b4.y, wb.y, acc2[r]);
          acc2[r] = fmaf(b4.z, wb.z, acc2[r]);
          acc2[r] = fmaf(b4.w, wb.w, acc2[r]);
        }
      }
    }
    __syncthreads();  // staging dead -> big becomes partial planes
    {
#pragma unroll
      for (int r = 0; r < 16; ++r) big[ks * 1024 + r * 64 + c] = acc1[r];
    }

    // ============ OUT-COLUMN GATE ============
    if (g >= 8) {
      if (tid == 0) {
        const unsigned need = (unsigned)(g - 7);
        while (rload(&ctrl[RDY_U(wg)]) < need) __builtin_amdgcn_s_sleep(1);
        __threadfence();
      }
    }
    __syncthreads();  // also orders planes-write vs reduce
    if (g >= 8 && tid < 128) {  // stage out[g-8] slice
      const int rr = tid >> 3, d = tid & 7;
      const int b = (rowBase + rr) & 31;
      sh_o[tid] = out[b * 960 + (g - 8) * 8 + d];
    }
    __syncthreads();
    {  // reduce A + bias + rank-8 fb injection -> sh_g
      const bool inj = (g >= 8) && valid;
#pragma unroll
      for (int e = 0; e < 2; ++e) {
        const int oi = tid + e * 512;
        const int r = oi >> 6, lc = oi & 63;
        const int j = (lc >> 4) * 256 + uc * 16 + (lc & 15);
        float sum = bih0[j] + bhh0[j];
#pragma unroll
        for (int kq = 0; kq < 8; ++kq) sum += big[kq * 1024 + oi];
        if (inj) {
#pragma unroll
          for (int d = 0; d < 8; ++d)
            sum += sh_o[r * 8 + d] * PW_ih0[(8 + d) * 64 + lc];
        }
        sh_g[oi] = sum;
      }
    }
    __syncthreads();
    if (tid < 256) {  // LSTM update, layer 0
      const int r = tid >> 4, u = tid & 15;
      const int grow = rowBase + r;
      const int gu = uc * 16 + u;
      const float iv = sh_g[r * 64 + u];
      const float fv = sh_g[r * 64 + 16 + u];
      const float gv = sh_g[r * 64 + 32 + u];
      const float ov = sh_g[r * 64 + 48 + u];
      const float cold = fresh ? 0.f : wsf[C0_F + grow * 256 + gu];
      const float cn = sigf(fv) * cold + sigf(iv) * tanhfast(gv);
      const float hn = sigf(ov) * tanhfast(cn);
      wsf[C0_F + grow * 256 + gu] = cn;
      wsf[(p ? H0A_F : H0B_F) + grow * 256 + gu] = hn;
    }
    pairbar(ctrl, pair, widx, ++seq);

    // ============ PHASE B (h0'-dependent part) ============
    {  // stage h0' -> big[0:4096]
      const float* h0w = wsf + (p ? H0A_F : H0B_F) + rowBase * 256;
      float4* B4 = (float4*)big;
#pragma unroll
      for (int i = 0; i < 2; ++i) {
        const int idx = tid + i * 512;
        B4[idx] = ((const float4*)h0w)[idx];
      }
    }
    __syncthreads();
    {  // acc2 += Wih1·h0'  (K=256)
      const float4* A4 = (const float4*)big;
#pragma unroll
      for (int kc = 0; kc < 8; ++kc) {
        const int kb4 = ks * 8 + kc;
        const float4 wa = PW_ih1[kb4 * 64 + c];
#pragma unroll
        for (int r = 0; r < 16; ++r) {
          const float4 a4 = A4[r * 64 + kb4];
          acc2[r] = fmaf(a4.x, wa.x, acc2[r]);
          acc2[r] = fmaf(a4.y, wa.y, acc2[r]);
          acc2[r] = fmaf(a4.z, wa.z, acc2[r]);
          acc2[r] = fmaf(a4.w, wa.w, acc2[r]);
        }
      }
    }
    __syncthreads();
    {
#pragma unroll
      for (int r = 0; r < 16; ++r) big[ks * 1024 + r * 64 + c] = acc2[r];
    }
    __syncthreads();
    {  // reduce B + bias -> sh_g
#pragma unroll
      for (int e = 0; e < 2; ++e) {
        const int oi = tid + e * 512;
        const int lc = oi & 63;
        const int j = (lc >> 4) * 256 + uc * 16 + (lc & 15);
        float sum = bih1[j] + bhh1[j];
#pragma unroll
        for (int kq = 0; kq < 8; ++kq) sum += big[kq * 1024 + oi];
        sh_g[oi] = sum;
      }
    }
    __syncthreads();
    if (tid < 256) {  // LSTM update, layer 1
      const int r = tid >> 4, u = tid & 15;
      const int grow = rowBase + r;
      const int gu = uc * 16 + u;
      const float iv = sh_g[r * 64 + u];
      const float fv = sh_g[r * 64 + 16 + u];
      const float gv = sh_g[r * 64 + 32 + u];
      const float ov = sh_g[r * 64 + 48 + u];
      const float cold = fresh ? 0.f : wsf[C1_F + grow * 256 + gu];
      const float cn = sigf(fv) * cold + sigf(iv) * tanhfast(gv);
      const float hn = sigf(ov) * tanhfast(cn);
      wsf[C1_F + grow * 256 + gu] = cn;
      wsf[(p ? H1A_F : H1B_F) + grow * 256 + gu] = hn;
    }
    pairbar(ctrl, pair, widx, ++seq);

    // ============ HEAD (pair leader of the finishing slot only) ============
    {
      const int tf = g - 7;
      if (tf >= 0 && pair == (tf & 7) && widx == 0) {
        if (tid < 256) {
          const int b = tid >> 3, o = tid & 7;
          const float4* h1 =
              (const float4*)(wsf + (p ? H1A_F : H1B_F) + (pair * 32 + b) * 256);
          const float4* wl = (const float4*)(Wlin + o * 256);
          float sum = blin[o];
#pragma unroll 8
          for (int u4 = 0; u4 < 64; ++u4) {
            const float4 h = h1[u4];
            const float4 w = wl[u4];
            sum = fmaf(h.x, w.x, sum);
            sum = fmaf(h.y, w.y, sum);
            sum = fmaf(h.z, w.z, sum);
            sum = fmaf(h.w, w.w, sum);
          }
          const float base = (tf == 0) ? traj[b * 2048 + 7 * 16 + 8 + o]
                                       : out[b * 960 + (tf - 1) * 8 + o];
          out[b * 960 + tf * 8 + o] = base + sum;
        }
        __syncthreads();  // drains out stores (vmcnt) for all waves
        if (tid < 256) rstore(&ctrl[RDY_U(tid)], (unsigned)(tf + 1));
      }
    }
  }

  // ---- epilogue: h_n/c_n = window 119 state (rows 224..255, parity-B bufs).
  //      Pair 7's own bars ordered these writes; no extra sync needed.
  if (rt >= 14) {
    const int idx = (rt - 14) * 16 + uc;   // 0..31
    const int i = idx * 1024 + tid * 2;    // 0..32767, step 2
    const int part = i >> 14;
    const int l = (i >> 13) & 1;
    const int b = (i >> 8) & 31;
    const int u = i & 255;
    const float* src =
        (part == 0) ? (l == 0 ? wsf + H0B_F : wsf + H1B_F)
                    : (l == 0 ? wsf + C0_F  : wsf + C1_F);
    const float2 v = *(const float2*)(src + (224 + b) * 256 + u);
    *(float2*)(out + 30720 + i) = v;
  }
}

extern "C" void kernel_launch(void* const* d_in, const int* in_sizes, int n_in,
                              void* d_out, int out_size, void* d_ws, size_t ws_size,
                              hipStream_t stream) {
  (void)in_sizes; (void)n_in; (void)out_size; (void)ws_size;
  const float* traj = (const float*)d_in[0];
  const float* Wih0 = (const float*)d_in[1];
  const float* Whh0 = (const float*)d_in[2];
  const float* bih0 = (const float*)d_in[3];
  const float* bhh0 = (const float*)d_in[4];
  const float* Wih1 = (const float*)d_in[5];
  const float* Whh1 = (const float*)d_in[6];
  const float* bih1 = (const float*)d_in[7];
  const float* bhh1 = (const float*)d_in[8];
  const float* Wlin = (const float*)d_in[9];
  const float* blin = (const float*)d_in[10];
  float* out = (float*)d_out;
  float* wsf = (float*)d_ws;

  hipMemsetAsync(d_ws, 0, CTRL_BYTES, stream);
  lstm_prep<<<1024, 256, 0, stream>>>(Wih0, Whh0, Wih1, Whh1, wsf);

  void* args[] = {(void*)&traj, (void*)&bih0, (void*)&bhh0, (void*)&bih1,
                  (void*)&bhh1, (void*)&Wlin, (void*)&blin, (void*)&out,
                  (void*)&wsf};
  hipLaunchCooperativeKernel((void*)lstm_main, dim3(NWG), dim3(TPB), args, 0,
                             stream);
}

// Round 5
// 12720.104 us; speedup vs baseline: 1.1093x; 1.1093x over previous
//
#include <hip/hip_runtime.h>

// OR_LSTM: 2-layer LSTM autoregressive rollout, wavefront-pipelined.
// B=32, T=128, D=16, H=256, WS=8, OUT=8. 120 windows over 127 iterations.
// Round 5: NO cache-maintenance ops in the loop (no threadfence, no
// acquire/release). All cross-wg state via RELAXED agent-scope atomics
// (MALL-coherent, L2-bypassing). c-state in registers. 16-wg group
// barriers (leader tree). Per-rt head (no pair scope). Weights L2-resident.

#define NWG 256
#define TPB 512

// ---- control region (u32 indices, zeroed by hipMemsetAsync) ----
#define ARR_U(rt, uc)  (((rt) * 16 + (uc)) * 16)          // arrival lines
#define RELB_U(rt, uc) (4096 + ((rt) * 16 + (uc)) * 16)   // release lines
#define RDYA_U(w)      (8192 + (w) * 16)                  // ready (even rt)
#define RDYB_U(w)      (12288 + (w) * 16)                 // ready (odd rt)
#define CTRL_BYTES     65536

// ---- float indices ----
#define H0A_F   16384
#define H0B_F   (H0A_F + 65536)
#define H1A_F   (H0B_F + 65536)
#define H1B_F   (H1A_F + 65536)
// packed weights: PW[uc][kb4][c][kk] (uc stride 16384 floats)
#define PWHH0_F (H1B_F + 65536)
#define PWIH1_F (PWHH0_F + 262144)
#define PWHH1_F (PWIH1_F + 262144)
#define PWIH0_F (PWHH1_F + 262144)   // [uc][k][c], k<16 (uc stride 1024)
// total 1081344 floats ~= 4.13 MiB

__device__ __forceinline__ float sigf(float x) { return 1.0f / (1.0f + __expf(-x)); }
__device__ __forceinline__ float tanhfast(float x) {
  float e = __expf(2.0f * x);
  return 1.0f - 2.0f / (e + 1.0f);
}

// Relaxed agent-scope atomics: MALL-coherent, NO buffer_inv / buffer_wbl2.
__device__ __forceinline__ unsigned rload(const unsigned* p) {
  return __hip_atomic_load(p, __ATOMIC_RELAXED, __HIP_MEMORY_SCOPE_AGENT);
}
__device__ __forceinline__ void rstore(unsigned* p, unsigned v) {
  __hip_atomic_store(p, v, __ATOMIC_RELAXED, __HIP_MEMORY_SCOPE_AGENT);
}
__device__ __forceinline__ float aload_f(const float* p) {
  union { unsigned u; float f; } cv;
  cv.u = __hip_atomic_load((const unsigned*)p, __ATOMIC_RELAXED,
                           __HIP_MEMORY_SCOPE_AGENT);
  return cv.f;
}
__device__ __forceinline__ void astore_f(float* p, float v) {
  union { float f; unsigned u; } cv;
  cv.f = v;
  __hip_atomic_store((unsigned*)p, cv.u, __ATOMIC_RELAXED,
                     __HIP_MEMORY_SCOPE_AGENT);
}
__device__ __forceinline__ float2 aload_f2(const float* p) {
  union { unsigned long long u; float2 f; } cv;
  cv.u = __hip_atomic_load((const unsigned long long*)p, __ATOMIC_RELAXED,
                           __HIP_MEMORY_SCOPE_AGENT);
  return cv.f;
}

// 16-wg group barrier, leader tree. Entry __syncthreads drains each wave's
// vmcnt (atomic data stores complete at MALL) before the arrival post.
__device__ __forceinline__ void groupbar16(unsigned* ctrl, int rt, int uc,
                                           unsigned seq) {
  __syncthreads();
  const int tid = threadIdx.x;
  if (uc == 0) {
    if (tid >= 1 && tid < 16) {
      const unsigned* a = &ctrl[ARR_U(rt, tid)];
      while (rload(a) < seq) __builtin_amdgcn_s_sleep(1);
      rstore(&ctrl[RELB_U(rt, tid)], seq);
    }
    __syncthreads();
  } else {
    if (tid == 0) {
      rstore(&ctrl[ARR_U(rt, uc)], seq);
      while (rload(&ctrl[RELB_U(rt, uc)]) < seq) __builtin_amdgcn_s_sleep(1);
    }
    __syncthreads();
  }
}

// Pack weights: PW[uc][kb4][c][kk] = W[j(c,uc)][kb4*4+kk].
__global__ __launch_bounds__(256) void lstm_prep(
    const float* __restrict__ Wih0, const float* __restrict__ Whh0,
    const float* __restrict__ Wih1, const float* __restrict__ Whh1,
    float* __restrict__ wsf) {
  const int i = blockIdx.x * 256 + threadIdx.x;
  if (i < 262144) {
    const int uc  = i >> 14;
    const int kb4 = (i >> 8) & 63;
    const int c   = (i >> 2) & 63;
    const int kk  = i & 3;
    const int k   = kb4 * 4 + kk;
    const int j   = (c >> 4) * 256 + uc * 16 + (c & 15);
    wsf[PWHH0_F + i] = Whh0[j * 256 + k];
    wsf[PWIH1_F + i] = Wih1[j * 256 + k];
    wsf[PWHH1_F + i] = Whh1[j * 256 + k];
    if (k < 16) wsf[PWIH0_F + uc * 1024 + k * 64 + c] = Wih0[j * 16 + k];
  }
}

__global__ __launch_bounds__(TPB, 2) void lstm_main(
    const float* __restrict__ traj,
    const float* __restrict__ bih0, const float* __restrict__ bhh0,
    const float* __restrict__ bih1, const float* __restrict__ bhh1,
    const float* __restrict__ Wlin, const float* __restrict__ blin,
    float* __restrict__ out, float* __restrict__ wsf) {
  __shared__ float big[8192];     // staging then partial planes
  __shared__ float sh_x[256];
  __shared__ float sh_g[1024];
  __shared__ float sh_o[128];
  __shared__ float sh_wfb[512];   // Wih0 feedback rows [d<8][c] (packed)
  __shared__ float sh_b0[64];     // bih0+bhh0 for this uc's 64 cols
  __shared__ float sh_b1[64];

  const int tid = threadIdx.x;
  const int wg  = blockIdx.x;
  const int rt  = wg >> 4;          // row tile (16 rows), 0..15
  const int uc  = wg & 15;          // unit chunk (16 hidden units)
  const int pair    = rt >> 1;      // pipeline slot 0..7
  const int rowBase = rt << 4;

  const int ks = tid >> 6;          // K-split 0..7 (wave id)
  const int c  = tid & 63;          // packed col 0..63

  unsigned* ctrl = (unsigned*)wsf;

  const float4* PW_hh0 = (const float4*)(wsf + PWHH0_F + uc * 16384);
  const float4* PW_ih1 = (const float4*)(wsf + PWIH1_F + uc * 16384);
  const float4* PW_hh1 = (const float4*)(wsf + PWHH1_F + uc * 16384);
  const float*  PW_ih0 = wsf + PWIH0_F + uc * 1024;

  // ---- one-time LDS prestage (iteration-invariant) ----
  sh_wfb[tid] = PW_ih0[(8 + (tid >> 6)) * 64 + (tid & 63)];
  if (tid < 64) {
    const int j = (tid >> 4) * 256 + uc * 16 + (tid & 15);
    sh_b0[tid] = bih0[j] + bhh0[j];
    sh_b1[tid] = bih1[j] + bhh1[j];
  }

  unsigned seq = 0;
  float acc1[16], acc2[16];
  float c0reg = 0.f, c1reg = 0.f;   // cell state in registers (tid<256)

  for (int g = 0; g < 127; ++g) {
    const int s = (g - pair) & 7;
    const int t = g - s;
    const bool valid = (t >= 0) && (t <= 119);
    const bool fresh = (s == 0) || (!valid);
    const int p = g & 1;

    // ============ PREWORK (ungated) ============
    if (tid < 256) {  // stage x: ctrl part (fb dims injected post-gate)
      const int r = tid >> 4, d = tid & 15;
      const int b = (rowBase + r) & 31;
      float xv = 0.0f;
      if (valid) {
        if (t <= 7 && s < 8 - t) {
          xv = traj[b * 2048 + (t + s) * 16 + d];   // raw window (g<8 only)
        } else if (d < 8) {
          const int ti = (t <= 7) ? (2 * t + s - 1) : (t + s);
          xv = traj[b * 2048 + ti * 16 + d];
        }
      }
      sh_x[tid] = xv;
    }
    {  // stage h0prev -> big[0:4096], h1prev -> big[4096:8192] (MALL loads)
      const float* h0r = wsf + (p ? H0B_F : H0A_F) + rowBase * 256;
      const float* h1r = wsf + (p ? H1B_F : H1A_F) + rowBase * 256;
      float2* B2 = (float2*)big;
      const float2 z = make_float2(0.f, 0.f);
#pragma unroll
      for (int i = 0; i < 4; ++i) {
        const int idx = tid + i * 512;
        B2[idx]        = fresh ? z : aload_f2(h0r + idx * 2);
        B2[2048 + idx] = fresh ? z : aload_f2(h1r + idx * 2);
      }
    }
    __syncthreads();

#pragma unroll
    for (int r = 0; r < 16; ++r) { acc1[r] = 0.f; acc2[r] = 0.f; }
    {  // bulk: Wih0·x_ctrl (K=16; fb dims zero here)
#pragma unroll
      for (int kk = 0; kk < 2; ++kk) {
        const int k = ks * 2 + kk;
        const float w = PW_ih0[k * 64 + c];
#pragma unroll
        for (int r = 0; r < 16; ++r)
          acc1[r] = fmaf(sh_x[r * 16 + k], w, acc1[r]);
      }
    }
    {  // bulk: Whh0·h0prev (acc1) + Whh1·h1prev (acc2), K=256
      const float4* A4 = (const float4*)big;
      const float4* B4 = A4 + 1024;
#pragma unroll
      for (int kc = 0; kc < 8; ++kc) {
        const int kb4 = ks * 8 + kc;
        const float4 wa = PW_hh0[kb4 * 64 + c];
        const float4 wb = PW_hh1[kb4 * 64 + c];
#pragma unroll
        for (int r = 0; r < 16; ++r) {
          const float4 a4 = A4[r * 64 + kb4];
          const float4 b4 = B4[r * 64 + kb4];
          acc1[r] = fmaf(a4.x, wa.x, acc1[r]);
          acc1[r] = fmaf(a4.y, wa.y, acc1[r]);
          acc1[r] = fmaf(a4.z, wa.z, acc1[r]);
          acc1[r] = fmaf(a4.w, wa.w, acc1[r]);
          acc2[r] = fmaf(b4.x, wb.x, acc2[r]);
          acc2[r] = fmaf(b4.y, wb.y, acc2[r]);
          acc2[r] = fmaf(b4.z, wb.z, acc2[r]);
          acc2[r] = fmaf(b4.w, wb.w, acc2[r]);
        }
      }
    }
    __syncthreads();  // staging dead -> big becomes partial planes
    {
#pragma unroll
      for (int r = 0; r < 16; ++r) big[ks * 1024 + r * 64 + c] = acc1[r];
    }

    // ============ OUT-COLUMN GATE ============
    if (g >= 8) {
      if (tid == 0) {
        const unsigned need = (unsigned)(g - 7);
        while (rload(&ctrl[RDYA_U(wg)]) < need) __builtin_amdgcn_s_sleep(1);
        while (rload(&ctrl[RDYB_U(wg)]) < need) __builtin_amdgcn_s_sleep(1);
      }
    }
    __syncthreads();  // also orders plane-writes vs reduce
    if (g >= 8 && tid < 128) {  // stage out[g-8] slice (MALL loads)
      const int rr = tid >> 3, d = tid & 7;
      const int b = (rowBase + rr) & 31;
      sh_o[tid] = aload_f(out + b * 960 + (g - 8) * 8 + d);
    }
    __syncthreads();
    {  // reduce + bias + rank-8 fb injection -> sh_g
      const bool inj = (g >= 8) && valid;
#pragma unroll
      for (int e = 0; e < 2; ++e) {
        const int oi = tid + e * 512;
        const int r = oi >> 6, lc = oi & 63;
        float sum = sh_b0[lc];
#pragma unroll
        for (int kq = 0; kq < 8; ++kq) sum += big[kq * 1024 + oi];
        if (inj) {
#pragma unroll
          for (int d = 0; d < 8; ++d)
            sum += sh_o[r * 8 + d] * sh_wfb[d * 64 + lc];
        }
        sh_g[oi] = sum;
      }
    }
    __syncthreads();
    if (tid < 256) {  // LSTM update, layer 0 (c in register)
      const int r = tid >> 4, u = tid & 15;
      const int grow = rowBase + r;
      const int gu = uc * 16 + u;
      const float iv = sh_g[r * 64 + u];
      const float fv = sh_g[r * 64 + 16 + u];
      const float gv = sh_g[r * 64 + 32 + u];
      const float ov = sh_g[r * 64 + 48 + u];
      const float cold = fresh ? 0.f : c0reg;
      const float cn = sigf(fv) * cold + sigf(iv) * tanhfast(gv);
      const float hn = sigf(ov) * tanhfast(cn);
      c0reg = cn;
      astore_f(wsf + (p ? H0A_F : H0B_F) + grow * 256 + gu, hn);
      if (g == 126 && rt >= 14) {  // h_n/c_n layer 0 (window 119 final)
        out[30720 + (grow - 224) * 256 + gu] = hn;
        out[47104 + (grow - 224) * 256 + gu] = cn;
      }
    }
    groupbar16(ctrl, rt, uc, ++seq);

    // ============ PHASE B (h0'-dependent) ============
    {  // stage h0' -> big[0:4096] (MALL loads)
      const float* h0w = wsf + (p ? H0A_F : H0B_F) + rowBase * 256;
      float2* B2 = (float2*)big;
#pragma unroll
      for (int i = 0; i < 4; ++i) {
        const int idx = tid + i * 512;
        B2[idx] = aload_f2(h0w + idx * 2);
      }
    }
    __syncthreads();
    {  // acc2 += Wih1·h0' (K=256)
      const float4* A4 = (const float4*)big;
#pragma unroll
      for (int kc = 0; kc < 8; ++kc) {
        const int kb4 = ks * 8 + kc;
        const float4 wa = PW_ih1[kb4 * 64 + c];
#pragma unroll
        for (int r = 0; r < 16; ++r) {
          const float4 a4 = A4[r * 64 + kb4];
          acc2[r] = fmaf(a4.x, wa.x, acc2[r]);
          acc2[r] = fmaf(a4.y, wa.y, acc2[r]);
          acc2[r] = fmaf(a4.z, wa.z, acc2[r]);
          acc2[r] = fmaf(a4.w, wa.w, acc2[r]);
        }
      }
    }
    __syncthreads();
    {
#pragma unroll
      for (int r = 0; r < 16; ++r) big[ks * 1024 + r * 64 + c] = acc2[r];
    }
    __syncthreads();
    {  // reduce + bias -> sh_g
#pragma unroll
      for (int e = 0; e < 2; ++e) {
        const int oi = tid + e * 512;
        float sum = sh_b1[oi & 63];
#pragma unroll
        for (int kq = 0; kq < 8; ++kq) sum += big[kq * 1024 + oi];
        sh_g[oi] = sum;
      }
    }
    __syncthreads();
    if (tid < 256) {  // LSTM update, layer 1
      const int r = tid >> 4, u = tid & 15;
      const int grow = rowBase + r;
      const int gu = uc * 16 + u;
      const float iv = sh_g[r * 64 + u];
      const float fv = sh_g[r * 64 + 16 + u];
      const float gv = sh_g[r * 64 + 32 + u];
      const float ov = sh_g[r * 64 + 48 + u];
      const float cold = fresh ? 0.f : c1reg;
      const float cn = sigf(fv) * cold + sigf(iv) * tanhfast(gv);
      const float hn = sigf(ov) * tanhfast(cn);
      c1reg = cn;
      astore_f(wsf + (p ? H1A_F : H1B_F) + grow * 256 + gu, hn);
      if (g == 126 && rt >= 14) {  // h_n/c_n layer 1
        out[30720 + 8192 + (grow - 224) * 256 + gu] = hn;
        out[47104 + 8192 + (grow - 224) * 256 + gu] = cn;
      }
    }
    groupbar16(ctrl, rt, uc, ++seq);

    // ============ HEAD (uc15 wg of each finishing rt) ============
    {
      const int tf = g - 7;
      if (tf >= 0 && uc == 15 && pair == (tf & 7)) {
        const int q = tid >> 7, idx = tid & 127;
        const int r = idx >> 3, o = idx & 7;
        const float* h1 =
            wsf + (p ? H1A_F : H1B_F) + (rowBase + r) * 256 + q * 64;
        const float2* wl2 = (const float2*)(Wlin + o * 256 + q * 64);
        float sum = 0.f;
#pragma unroll 8
        for (int k2 = 0; k2 < 32; ++k2) {
          const float2 h = aload_f2(h1 + k2 * 2);
          const float2 w = wl2[k2];
          sum = fmaf(h.x, w.x, sum);
          sum = fmaf(h.y, w.y, sum);
        }
        sh_g[q * 128 + idx] = sum;
        __syncthreads();
        if (tid < 128) {
          const int b = (rowBase + (tid >> 3)) & 31;
          const int oo = tid & 7;
          const float pred =
              sh_g[tid] + sh_g[128 + tid] + sh_g[256 + tid] + sh_g[384 + tid] +
              blin[oo];
          const float base = (tf == 0)
                                 ? traj[b * 2048 + 7 * 16 + 8 + oo]
                                 : aload_f(out + b * 960 + (tf - 1) * 8 + oo);
          astore_f(out + b * 960 + tf * 8 + oo, base + pred);
        }
        __syncthreads();  // drains out stores (vmcnt) before RDY posts
        if (tid < 256) {
          if ((rt & 1) == 0) rstore(&ctrl[RDYA_U(tid)], (unsigned)(tf + 1));
          else               rstore(&ctrl[RDYB_U(tid)], (unsigned)(tf + 1));
        }
      }
    }
  }
}

extern "C" void kernel_launch(void* const* d_in, const int* in_sizes, int n_in,
                              void* d_out, int out_size, void* d_ws, size_t ws_size,
                              hipStream_t stream) {
  (void)in_sizes; (void)n_in; (void)out_size; (void)ws_size;
  const float* traj = (const float*)d_in[0];
  const float* Wih0 = (const float*)d_in[1];
  const float* Whh0 = (const float*)d_in[2];
  const float* bih0 = (const float*)d_in[3];
  const float* bhh0 = (const float*)d_in[4];
  const float* Wih1 = (const float*)d_in[5];
  const float* Whh1 = (const float*)d_in[6];
  const float* bih1 = (const float*)d_in[7];
  const float* bhh1 = (const float*)d_in[8];
  const float* Wlin = (const float*)d_in[9];
  const float* blin = (const float*)d_in[10];
  float* out = (float*)d_out;
  float* wsf = (float*)d_ws;

  hipMemsetAsync(d_ws, 0, CTRL_BYTES, stream);
  lstm_prep<<<1024, 256, 0, stream>>>(Wih0, Whh0, Wih1, Whh1, wsf);

  void* args[] = {(void*)&traj, (void*)&bih0, (void*)&bhh0, (void*)&bih1,
                  (void*)&bhh1, (void*)&Wlin, (void*)&blin, (void*)&out,
                  (void*)&wsf};
  hipLaunchCooperativeKernel((void*)lstm_main, dim3(NWG), dim3(TPB), args, 0,
                             stream);
}